// Round 4
// baseline (4583.149 us; speedup 1.0000x reference)
//
#include <hip/hip_runtime.h>
#include <stdint.h>
#include <stddef.h>

#define T_LEN  512
#define BATCH  64
#define NTAG   13
#define CT     64
#define NCHUNK 8

__device__ __forceinline__ float sigm(float x) { return 1.0f / (1.0f + expf(-x)); }

// ---------------------------------------------------------------------------
// Kernel 1: input-side GEMM for one 64-step chunk (both directions).
//   xg_ws[d][j][gate(1024)][b(64)] = emb[x[b][t]] . w_ih_d[gate] + b_ih + b_hh
// grid (8, 32, 2), block 256. Block tile: 128 gates x 128 cols, 8x8/thread.
// ---------------------------------------------------------------------------
__global__ __launch_bounds__(256) void xg_gemm(
    const int* __restrict__ x, const float* __restrict__ emb,
    const float* __restrict__ w_ih_f, const float* __restrict__ w_ih_b,
    const float* __restrict__ b_ih_f, const float* __restrict__ b_hh_f,
    const float* __restrict__ b_ih_b, const float* __restrict__ b_hh_b,
    float* __restrict__ xg_ws, int chunk)
{
    const int tid = threadIdx.x;
    const int mt = blockIdx.x;
    const int nt = blockIdx.y;
    const int d  = blockIdx.z;
    const int tbase = (d == 0 ? chunk : (NCHUNK - 1 - chunk)) * CT;
    const float* W  = (d == 0) ? w_ih_f : w_ih_b;
    const float* bi = (d == 0) ? b_ih_f : b_ih_b;
    const float* bh = (d == 0) ? b_hh_f : b_hh_b;

    __shared__ __align__(16) float Wl[16][132];
    __shared__ __align__(16) float El[16][132];
    __shared__ int tok[128];

    if (tid < 128) {
        int col = nt * 128 + tid;
        tok[tid] = x[(col & 63) * T_LEN + tbase + (col >> 6)];
    }
    __syncthreads();

    const int r  = tid >> 1;
    const int c8 = (tid & 1) * 8;
    const int tm = tid >> 4;
    const int tn = tid & 15;

    float acc[8][8];
#pragma unroll
    for (int i = 0; i < 8; i++)
#pragma unroll
        for (int jz = 0; jz < 8; jz++) acc[i][jz] = 0.0f;

    const float* wrow = &W[(size_t)(mt * 128 + r) * 256];
    const float* erow = &emb[(size_t)tok[r] * 256];

    for (int kb = 0; kb < 256; kb += 16) {
        float4 w0 = *(const float4*)&wrow[kb + c8];
        float4 w1 = *(const float4*)&wrow[kb + c8 + 4];
        float4 e0 = *(const float4*)&erow[kb + c8];
        float4 e1 = *(const float4*)&erow[kb + c8 + 4];
        __syncthreads();
        Wl[c8+0][r] = w0.x; Wl[c8+1][r] = w0.y; Wl[c8+2][r] = w0.z; Wl[c8+3][r] = w0.w;
        Wl[c8+4][r] = w1.x; Wl[c8+5][r] = w1.y; Wl[c8+6][r] = w1.z; Wl[c8+7][r] = w1.w;
        El[c8+0][r] = e0.x; El[c8+1][r] = e0.y; El[c8+2][r] = e0.z; El[c8+3][r] = e0.w;
        El[c8+4][r] = e1.x; El[c8+5][r] = e1.y; El[c8+6][r] = e1.z; El[c8+7][r] = e1.w;
        __syncthreads();
#pragma unroll
        for (int kk = 0; kk < 16; kk++) {
            float a[8], b[8];
            *(float4*)&a[0] = *(const float4*)&Wl[kk][tm*8];
            *(float4*)&a[4] = *(const float4*)&Wl[kk][tm*8+4];
            *(float4*)&b[0] = *(const float4*)&El[kk][tn*8];
            *(float4*)&b[4] = *(const float4*)&El[kk][tn*8+4];
#pragma unroll
            for (int i = 0; i < 8; i++)
#pragma unroll
                for (int jz = 0; jz < 8; jz++)
                    acc[i][jz] += a[i] * b[jz];
        }
    }

    const int colbase = nt * 128 + tn * 8;
    const int j  = colbase >> 6;
    const int b0 = colbase & 63;
#pragma unroll
    for (int gi = 0; gi < 8; gi++) {
        int g = mt * 128 + tm * 8 + gi;
        float bias = bi[g] + bh[g];
        float* dst = &xg_ws[(((size_t)(d * CT + j) * 1024 + g) << 6) + b0];
        float4 v0 = make_float4(acc[gi][0]+bias, acc[gi][1]+bias, acc[gi][2]+bias, acc[gi][3]+bias);
        float4 v1 = make_float4(acc[gi][4]+bias, acc[gi][5]+bias, acc[gi][6]+bias, acc[gi][7]+bias);
        *(float4*)dst       = v0;
        *(float4*)(dst + 4) = v1;
    }
}

// ---------------------------------------------------------------------------
// Kernel 2: persistent chunked LSTM.
// R4 structure: 128 blocks = [dg: 2 dir x 4 sgroups of 16 samples] x
// [16 slices of 16 h-units]. Per block: 64 gate rows x 256 K in LDS (66.5 KB,
// gfx950 allows up to 160 KB/workgroup). 16 peers per sync group (was 32) --
// halves straggler tail. Sync stays R3-style: relaxed sc1 atomics only, no
// acquire/release cache maintenance. Poll: spin-first, then s_sleep(2).
// ---------------------------------------------------------------------------
__global__ __launch_bounds__(256) void lstm_chunk(
    const float* __restrict__ xg_ws,
    const float* __restrict__ w_hh_f, const float* __restrict__ w_hh_b,
    float* h_ex, float* c_state, float* h_all, int* flags, int chunk)
{
    const int tid = threadIdx.x;
    const int bid = blockIdx.x;      // 0..127
    const int dg    = bid & 7;       // dir = dg&1, sgroup = dg>>1
    const int slice = bid >> 3;      // 0..15
    const int dir = dg & 1;
    const int sg  = dg >> 1;
    const int h_base = slice * 16;   // 16 h-units per slice
    const int sbase  = sg * 16;

    __shared__ __align__(16) float w_lds[64][260];   // 64 gate rows x 256 K (66.5 KB)
    __shared__ __align__(16) float h_lds[16][260];   // 16 samples x 256 h (16.6 KB)
    __shared__ __align__(16) float red[4][32][36];   // k-split reduction (18.4 KB)
    __shared__ float gatebuf[64][17];                // 4.4 KB

    const float* W = dir ? w_hh_b : w_hh_f;
    // rows rr=0..63 -> gate (rr>>4), h-unit h_base+(rr&15); 64 f4-cols each
    for (int idx = tid; idx < 4096; idx += 256) {
        int rr = idx >> 6;
        int c4 = (idx & 63) << 2;
        int row = (rr >> 4) * 256 + h_base + (rr & 15);
        *(float4*)&w_lds[rr][c4] = *(const float4*)&W[(size_t)row * 256 + c4];
    }

    const int s_g  = tid & 15;       // sample 0..15
    const int ih_g = tid >> 4;       // h-unit 0..15
    float c_val = c_state[(size_t)(dir * 64 + sbase + s_g) * 256 + h_base + ih_g];

    {   // initial h fill (parity-0 buffer holds prior chunk's final state)
        const int s = tid >> 4, tn = tid & 15;
        const float* src = &h_ex[((size_t)dg * 16 + s) * 256];
#pragma unroll
        for (int i = 0; i < 16; i++)
            h_lds[s][tn + 16 * i] =
                __hip_atomic_load(&src[tn + 16 * i], __ATOMIC_RELAXED, __HIP_MEMORY_SCOPE_AGENT);
    }
    __syncthreads();

    const int kc   = tid >> 5;       // 0..7 k-split (32 K each)
    const int tile = tid & 31;
    const int rowt = tile >> 2;      // 0..7: rows rowt + ri*8
    const int st   = tile & 3;       // 0..3: samples st + si*4
    const float* wrp[8];
#pragma unroll
    for (int i = 0; i < 8; i++) wrp[i] = &w_lds[rowt + i * 8][0];
    const float* hrp[4];
#pragma unroll
    for (int i = 0; i < 4; i++) hrp[i] = &h_lds[st + i * 4][0];

    // preload xg for first step
    float xg0 = 0.f, xg1 = 0.f, xg2 = 0.f, xg3 = 0.f;
    {
        const int jslot0 = dir ? (CT - 1) : 0;
        const float* xp = &xg_ws[(((size_t)(dir * CT + jslot0) * 1024) + h_base + ih_g) * 64 + sbase + s_g];
        xg0 = xp[0];
        xg1 = xp[1 * 256 * 64];
        xg2 = xp[2 * 256 * 64];
        xg3 = xp[3 * 256 * 64];
    }

#pragma unroll 1
    for (int tl = 0; tl < CT; tl++) {
        const int jslot = dir ? (CT - 1 - tl) : tl;
        const int t = (dir ? (NCHUNK - 1 - chunk) : chunk) * CT + jslot;
        const int sc = chunk * CT + tl + 1;
        const int par = sc & 1;

        float acc[8][4];
#pragma unroll
        for (int ri = 0; ri < 8; ri++)
#pragma unroll
            for (int si = 0; si < 4; si++) acc[ri][si] = 0.0f;

        const int j0 = kc * 32;
#pragma unroll
        for (int m = 0; m < 8; m++) {
            const int jj = j0 + m * 4;
            float4 h4[4];
#pragma unroll
            for (int i = 0; i < 4; i++) h4[i] = *(const float4*)(hrp[i] + jj);
#pragma unroll
            for (int ri = 0; ri < 8; ri++) {
                float4 w4 = *(const float4*)(wrp[ri] + jj);
#pragma unroll
                for (int si = 0; si < 4; si++)
                    acc[ri][si] += w4.x*h4[si].x + w4.y*h4[si].y
                                 + w4.z*h4[si].z + w4.w*h4[si].w;
            }
        }

        // two-phase k-split reduction (8 -> 4 -> 1)
        if (kc >= 4) {
#pragma unroll
            for (int ri = 0; ri < 8; ri++)
                *(float4*)&red[kc-4][tile][ri*4] =
                    make_float4(acc[ri][0], acc[ri][1], acc[ri][2], acc[ri][3]);
        }
        __syncthreads();
        if (kc < 4) {
#pragma unroll
            for (int ri = 0; ri < 8; ri++) {
                float4 v = *(const float4*)&red[kc][tile][ri*4];
                acc[ri][0] += v.x; acc[ri][1] += v.y; acc[ri][2] += v.z; acc[ri][3] += v.w;
            }
        }
        __syncthreads();
        if (kc >= 1 && kc < 4) {
#pragma unroll
            for (int ri = 0; ri < 8; ri++)
                *(float4*)&red[kc-1][tile][ri*4] =
                    make_float4(acc[ri][0], acc[ri][1], acc[ri][2], acc[ri][3]);
        }
        __syncthreads();
        if (kc == 0) {
#pragma unroll
            for (int p = 0; p < 3; p++)
#pragma unroll
                for (int ri = 0; ri < 8; ri++) {
                    float4 v = *(const float4*)&red[p][tile][ri*4];
                    acc[ri][0] += v.x; acc[ri][1] += v.y; acc[ri][2] += v.z; acc[ri][3] += v.w;
                }
#pragma unroll
            for (int ri = 0; ri < 8; ri++)
#pragma unroll
                for (int si = 0; si < 4; si++)
                    gatebuf[rowt + ri*8][st + si*4] = acc[ri][si];
        }
        __syncthreads();

        // nonlinearity: all 256 threads, one (h,s) cell each
        float gI = gatebuf[     ih_g][s_g] + xg0;
        float gF = gatebuf[16 + ih_g][s_g] + xg1;
        float gG = gatebuf[32 + ih_g][s_g] + xg2;
        float gO = gatebuf[48 + ih_g][s_g] + xg3;
        c_val = sigm(gF) * c_val + sigm(gI) * tanhf(gG);
        float hv = sigm(gO) * tanhf(c_val);
        __hip_atomic_store(&h_ex[(((size_t)par * 8 + dg) * 16 + s_g) * 256 + h_base + ih_g],
                           hv, __ATOMIC_RELAXED, __HIP_MEMORY_SCOPE_AGENT);
        __syncthreads();   // compiler emits vmcnt(0) before s_barrier -> h_ex committed at L3

        // arrive (relaxed store, own slot)
        if (tid == 0)
            __hip_atomic_store(&flags[dg * 16 + slice], sc, __ATOMIC_RELAXED, __HIP_MEMORY_SCOPE_AGENT);

        // off-critical-path: h_all store + next-step xg prefetch
        h_all[((size_t)t * 64 + sbase + s_g) * 512 + dir * 256 + h_base + ih_g] = hv;
        if (tl + 1 < CT) {
            const int jn = dir ? (jslot - 1) : (jslot + 1);
            const float* xp = &xg_ws[(((size_t)(dir * CT + jn) * 1024) + h_base + ih_g) * 64 + sbase + s_g];
            xg0 = xp[0];
            xg1 = xp[1 * 256 * 64];
            xg2 = xp[2 * 256 * 64];
            xg3 = xp[3 * 256 * 64];
        }

        // wait: one wave, coalesced relaxed poll; spin first, then backoff
        if (tid < 64) {
            const int* fp = &flags[dg * 16 + (tid & 15)];
            int spins = 0;
            int v = __hip_atomic_load(fp, __ATOMIC_RELAXED, __HIP_MEMORY_SCOPE_AGENT);
            while (__ballot(v < sc) != 0ull) {
                if (++spins > 4) __builtin_amdgcn_s_sleep(2);
                v = __hip_atomic_load(fp, __ATOMIC_RELAXED, __HIP_MEMORY_SCOPE_AGENT);
                if (spins > (1 << 20)) break;   // safety valve; co-residency guaranteed
            }
        }
        __syncthreads();

        {   // reload peer h (relaxed sc1 loads read the coherence point)
            const int s = tid >> 4, tn = tid & 15;
            const float* src = &h_ex[(((size_t)par * 8 + dg) * 16 + s) * 256];
#pragma unroll
            for (int i = 0; i < 16; i++)
                h_lds[s][tn + 16 * i] =
                    __hip_atomic_load(&src[tn + 16 * i], __ATOMIC_RELAXED, __HIP_MEMORY_SCOPE_AGENT);
        }
        __syncthreads();
    }

    c_state[(size_t)(dir * 64 + sbase + s_g) * 256 + h_base + ih_g] = c_val;
}

// ---------------------------------------------------------------------------
__global__ __launch_bounds__(256) void emis_kernel(
    const float* __restrict__ h_all, const float* __restrict__ w_out,
    const float* __restrict__ b_out, float* __restrict__ emis)
{
    const int row = blockIdx.x * 16 + (threadIdx.x >> 4);
    const int k   = threadIdx.x & 15;
    const float* hr = &h_all[(size_t)row * 512];
    const float* wr = &w_out[(size_t)(k < NTAG ? k : 0) * 512];
    float acc = 0.0f;
#pragma unroll 8
    for (int e = 0; e < 512; e += 4) {
        float4 h4 = *(const float4*)&hr[e];
        float4 w4 = *(const float4*)&wr[e];
        acc += h4.x*w4.x + h4.y*w4.y + h4.z*w4.z + h4.w*w4.w;
    }
    if (k < NTAG) emis[(size_t)row * NTAG + k] = acc + b_out[k];
}

// ---------------------------------------------------------------------------
__global__ __launch_bounds__(64) void viterbi_kernel(
    const float* __restrict__ emis, const float* __restrict__ start_trans,
    const float* __restrict__ end_trans, const float* __restrict__ trans,
    float* __restrict__ out)
{
    const int b = blockIdx.x;
    const int k = threadIdx.x;
    __shared__ float em[T_LEN * NTAG];
    __shared__ unsigned char bp[T_LEN][16];

    for (int t = k; t < T_LEN; t += 64) {
        const float* src = &emis[((size_t)t * 64 + b) * NTAG];
#pragma unroll
        for (int kk = 0; kk < NTAG; kk++)
            em[t * NTAG + kk] = src[kk];
    }
    __syncthreads();

    float tc[NTAG];
#pragma unroll
    for (int kp = 0; kp < NTAG; kp++)
        tc[kp] = (k < NTAG) ? trans[kp * NTAG + k] : 0.0f;

    float score = (k < NTAG) ? (start_trans[k] + em[k]) : -3.0e38f;

    for (int t = 1; t < T_LEN; t++) {
        float best = -3.0e38f;
        int bi = 0;
#pragma unroll
        for (int kp = 0; kp < NTAG; kp++) {
            float v = __shfl(score, kp) + tc[kp];
            if (v > best) { best = v; bi = kp; }   // strict > => first max (jnp.argmax)
        }
        if (k < NTAG) {
            score = best + em[t * NTAG + k];
            bp[t][k] = (unsigned char)bi;
        }
    }
    if (k < NTAG) score += end_trans[k];
    else score = -3.0e38f;
    __syncthreads();

    float bs = -3.0e38f;
    int tag = 0;
#pragma unroll
    for (int kk = 0; kk < NTAG; kk++) {
        float v = __shfl(score, kk);
        if (v > bs) { bs = v; tag = kk; }
    }
    if (k == 0) {
        out[32768 + b] = bs;
        int tg = tag;
        out[b * T_LEN + (T_LEN - 1)] = (float)tg;
        for (int t = T_LEN - 1; t >= 1; t--) {
            tg = bp[t][tg];
            out[b * T_LEN + t - 1] = (float)tg;
        }
    }
}

// ---------------------------------------------------------------------------
extern "C" void kernel_launch(void* const* d_in, const int* in_sizes, int n_in,
                              void* d_out, int out_size, void* d_ws, size_t ws_size,
                              hipStream_t stream)
{
    (void)in_sizes; (void)n_in; (void)out_size; (void)ws_size;
    const int*   x    = (const int*)  d_in[0];
    const float* emb  = (const float*)d_in[1];
    const float* wihf = (const float*)d_in[2];
    const float* whhf = (const float*)d_in[3];
    const float* bihf = (const float*)d_in[4];
    const float* bhhf = (const float*)d_in[5];
    const float* wihb = (const float*)d_in[6];
    const float* whhb = (const float*)d_in[7];
    const float* bihb = (const float*)d_in[8];
    const float* bhhb = (const float*)d_in[9];
    const float* wout = (const float*)d_in[10];
    const float* bout = (const float*)d_in[11];
    const float* stt  = (const float*)d_in[12];
    const float* ent  = (const float*)d_in[13];
    const float* trn  = (const float*)d_in[14];
    float* out = (float*)d_out;

    char* ws = (char*)d_ws;
    size_t off = 0;
    float* xg_ws = (float*)(ws + off); off += (size_t)2 * CT * 1024 * 64 * 4;   // 33.55 MB
    float* h_all = (float*)(ws + off); off += (size_t)T_LEN * 64 * 512 * 4;     // 67.11 MB
    float* h_ex  = (float*)(ws + off); off += (size_t)2 * 8 * 16 * 256 * 4;     // 256 KB
    float* c_st  = (float*)(ws + off); off += (size_t)2 * 64 * 256 * 4;         // 128 KB
    float* emis  = (float*)(ws + off); off += (size_t)T_LEN * 64 * NTAG * 4;    // 1.70 MB
    int*   flags = (int*)  (ws + off); off += 8 * 16 * 4;

    hipMemsetAsync(h_ex,  0, (size_t)2 * 8 * 16 * 256 * 4, stream);
    hipMemsetAsync(c_st,  0, (size_t)2 * 64 * 256 * 4, stream);
    hipMemsetAsync(flags, 0, 8 * 16 * 4, stream);

    for (int c = 0; c < NCHUNK; c++) {
        xg_gemm<<<dim3(8, 32, 2), 256, 0, stream>>>(x, emb, wihf, wihb,
                                                    bihf, bhhf, bihb, bhhb, xg_ws, c);
        lstm_chunk<<<128, 256, 0, stream>>>(xg_ws, whhf, whhb, h_ex, c_st, h_all, flags, c);
    }
    emis_kernel<<<2048, 256, 0, stream>>>(h_all, wout, bout, emis);
    viterbi_kernel<<<64, 64, 0, stream>>>(emis, stt, ent, trn, out);
}

// Round 5
// 3460.903 us; speedup vs baseline: 1.3243x; 1.3243x over previous
//
#include <hip/hip_runtime.h>
#include <stdint.h>
#include <stddef.h>

#define T_LEN  512
#define BATCH  64
#define NTAG   13
#define CT     64
#define NCHUNK 8

__device__ __forceinline__ float sigm(float x) { return 1.0f / (1.0f + expf(-x)); }

// ---------------------------------------------------------------------------
// Kernel 1: input-side GEMM for one 64-step chunk (both directions).
// ---------------------------------------------------------------------------
__global__ __launch_bounds__(256) void xg_gemm(
    const int* __restrict__ x, const float* __restrict__ emb,
    const float* __restrict__ w_ih_f, const float* __restrict__ w_ih_b,
    const float* __restrict__ b_ih_f, const float* __restrict__ b_hh_f,
    const float* __restrict__ b_ih_b, const float* __restrict__ b_hh_b,
    float* __restrict__ xg_ws, int chunk)
{
    const int tid = threadIdx.x;
    const int mt = blockIdx.x;
    const int nt = blockIdx.y;
    const int d  = blockIdx.z;
    const int tbase = (d == 0 ? chunk : (NCHUNK - 1 - chunk)) * CT;
    const float* W  = (d == 0) ? w_ih_f : w_ih_b;
    const float* bi = (d == 0) ? b_ih_f : b_ih_b;
    const float* bh = (d == 0) ? b_hh_f : b_hh_b;

    __shared__ __align__(16) float Wl[16][132];
    __shared__ __align__(16) float El[16][132];
    __shared__ int tok[128];

    if (tid < 128) {
        int col = nt * 128 + tid;
        tok[tid] = x[(col & 63) * T_LEN + tbase + (col >> 6)];
    }
    __syncthreads();

    const int r  = tid >> 1;
    const int c8 = (tid & 1) * 8;
    const int tm = tid >> 4;
    const int tn = tid & 15;

    float acc[8][8];
#pragma unroll
    for (int i = 0; i < 8; i++)
#pragma unroll
        for (int jz = 0; jz < 8; jz++) acc[i][jz] = 0.0f;

    const float* wrow = &W[(size_t)(mt * 128 + r) * 256];
    const float* erow = &emb[(size_t)tok[r] * 256];

    for (int kb = 0; kb < 256; kb += 16) {
        float4 w0 = *(const float4*)&wrow[kb + c8];
        float4 w1 = *(const float4*)&wrow[kb + c8 + 4];
        float4 e0 = *(const float4*)&erow[kb + c8];
        float4 e1 = *(const float4*)&erow[kb + c8 + 4];
        __syncthreads();
        Wl[c8+0][r] = w0.x; Wl[c8+1][r] = w0.y; Wl[c8+2][r] = w0.z; Wl[c8+3][r] = w0.w;
        Wl[c8+4][r] = w1.x; Wl[c8+5][r] = w1.y; Wl[c8+6][r] = w1.z; Wl[c8+7][r] = w1.w;
        El[c8+0][r] = e0.x; El[c8+1][r] = e0.y; El[c8+2][r] = e0.z; El[c8+3][r] = e0.w;
        El[c8+4][r] = e1.x; El[c8+5][r] = e1.y; El[c8+6][r] = e1.z; El[c8+7][r] = e1.w;
        __syncthreads();
#pragma unroll
        for (int kk = 0; kk < 16; kk++) {
            float a[8], b[8];
            *(float4*)&a[0] = *(const float4*)&Wl[kk][tm*8];
            *(float4*)&a[4] = *(const float4*)&Wl[kk][tm*8+4];
            *(float4*)&b[0] = *(const float4*)&El[kk][tn*8];
            *(float4*)&b[4] = *(const float4*)&El[kk][tn*8+4];
#pragma unroll
            for (int i = 0; i < 8; i++)
#pragma unroll
                for (int jz = 0; jz < 8; jz++)
                    acc[i][jz] += a[i] * b[jz];
        }
    }

    const int colbase = nt * 128 + tn * 8;
    const int j  = colbase >> 6;
    const int b0 = colbase & 63;
#pragma unroll
    for (int gi = 0; gi < 8; gi++) {
        int g = mt * 128 + tm * 8 + gi;
        float bias = bi[g] + bh[g];
        float* dst = &xg_ws[(((size_t)(d * CT + j) * 1024 + g) << 6) + b0];
        float4 v0 = make_float4(acc[gi][0]+bias, acc[gi][1]+bias, acc[gi][2]+bias, acc[gi][3]+bias);
        float4 v1 = make_float4(acc[gi][4]+bias, acc[gi][5]+bias, acc[gi][6]+bias, acc[gi][7]+bias);
        *(float4*)dst       = v0;
        *(float4*)(dst + 4) = v1;
    }
}

// ---------------------------------------------------------------------------
// Kernel 2: persistent chunked LSTM. R3 geometry (256 blocks = 8 dg x 32
// slices of 8 h-units), R5 critical-path cuts:
//  - poll wave issues NOTHING between arrive and poll (h_all store + xg
//    prefetch moved to top of next iteration, drain under GEMM)
//  - h_ex stores coalesced (ih = tid&7 lane-fastest -> 32-B segments)
//  - reload via 8-byte relaxed sc1 atomic loads + ds_write_b64 (coalesced,
//    still bypasses L1/L2 for cross-block correctness)
//  - single-phase 8->1 k-split reduction (2 barriers, was 4)
//  - spin-first poll, then s_sleep(1)
// Sync mechanism unchanged from R3: relaxed sc1 atomics only, no
// acquire/release (no buffer_inv/wbl2 — the R1/R2 killer).
// ---------------------------------------------------------------------------
__global__ __launch_bounds__(256) void lstm_chunk(
    const float* __restrict__ xg_ws,
    const float* __restrict__ w_hh_f, const float* __restrict__ w_hh_b,
    float* h_ex, float* c_state, float* h_all, int* flags, int chunk)
{
    const int tid = threadIdx.x;
    const int bid = blockIdx.x;
    const int dg    = bid & 7;
    const int slice = bid >> 3;      // 0..31
    const int dir = dg & 1;
    const int grp = dg >> 1;
    const int h_base = slice * 8;
    const int sbase  = grp * 16;

    __shared__ __align__(16) float w_lds[32][260];
    __shared__ __align__(16) float h_lds[16][260];
    __shared__ __align__(16) float red[7][32][20];
    __shared__ float gatebuf[32][17];

    const float* W = dir ? w_hh_b : w_hh_f;
    for (int idx = tid; idx < 2048; idx += 256) {     // f4 weight fill
        int f  = idx << 2;
        int rr = f >> 8;
        int c4 = f & 255;
        int row = (rr >> 3) * 256 + h_base + (rr & 7);
        *(float4*)&w_lds[rr][c4] = *(const float4*)&W[(size_t)row * 256 + c4];
    }

    // nonlin-phase mapping (tid<128): ih lane-fastest for coalesced stores
    const int ih_g = tid & 7;
    const int s_g  = tid >> 3;       // 0..15 (for tid<128)
    float c_val = 0.0f;
    if (tid < 128)
        c_val = c_state[(size_t)(dir * 64 + sbase + s_g) * 256 + h_base + ih_g];

    {   // initial h fill from parity-0 buffer (prior chunk ends at even sc)
        const float* base = &h_ex[((size_t)dg * 16) * 256];
#pragma unroll
        for (int i = 0; i < 8; i++) {
            int pos = tid + 256 * i;         // 8-byte units
            int fo  = pos << 1;
            unsigned long long u64 = __hip_atomic_load(
                (const unsigned long long*)(base + fo), __ATOMIC_RELAXED, __HIP_MEMORY_SCOPE_AGENT);
            float2 v = __builtin_bit_cast(float2, u64);
            *(float2*)&h_lds[fo >> 8][fo & 255] = v;
        }
    }
    __syncthreads();

    const int kc   = tid >> 5;       // 0..7 k-split
    const int tile = tid & 31;
    const int gt = tile >> 2;        // rows gt + 8*gi
    const int st = tile & 3;         // samples st + 4*si
    const float* wr[4] = { &w_lds[gt][0], &w_lds[8+gt][0], &w_lds[16+gt][0], &w_lds[24+gt][0] };
    const float* hr[4] = { &h_lds[st][0], &h_lds[4+st][0], &h_lds[8+st][0],  &h_lds[12+st][0] };

    float hv_prev = 0.0f;
    size_t ha_prev = 0;

#pragma unroll 1
    for (int tl = 0; tl < CT; tl++) {
        const int jslot = dir ? (CT - 1 - tl) : tl;
        const int t = (dir ? (NCHUNK - 1 - chunk) : chunk) * CT + jslot;
        const int sc = chunk * CT + tl + 1;
        const int par = sc & 1;

        // top-of-loop issues: drain under the GEMM below
        float xg0 = 0.f, xg1 = 0.f, xg2 = 0.f, xg3 = 0.f;
        if (tid < 128) {
            if (tl > 0) h_all[ha_prev] = hv_prev;
            const float* xp = &xg_ws[(((size_t)(dir * CT + jslot) * 1024) + h_base + ih_g) * 64 + sbase + s_g];
            xg0 = xp[0];
            xg1 = xp[1 * 256 * 64];
            xg2 = xp[2 * 256 * 64];
            xg3 = xp[3 * 256 * 64];
        }

        float acc[4][4];
#pragma unroll
        for (int gi = 0; gi < 4; gi++)
#pragma unroll
            for (int si = 0; si < 4; si++) acc[gi][si] = 0.0f;

        const int j0 = kc * 32;
#pragma unroll
        for (int m = 0; m < 8; m++) {
            const int jj = j0 + m * 4;
            float4 w4[4], h4[4];
#pragma unroll
            for (int i = 0; i < 4; i++) w4[i] = *(const float4*)(wr[i] + jj);
#pragma unroll
            for (int i = 0; i < 4; i++) h4[i] = *(const float4*)(hr[i] + jj);
#pragma unroll
            for (int gi = 0; gi < 4; gi++)
#pragma unroll
                for (int si = 0; si < 4; si++)
                    acc[gi][si] += w4[gi].x*h4[si].x + w4[gi].y*h4[si].y
                                 + w4[gi].z*h4[si].z + w4[gi].w*h4[si].w;
        }

        // single-phase 8->1 k-split reduction
        if (kc >= 1) {
#pragma unroll
            for (int gi = 0; gi < 4; gi++)
                *(float4*)&red[kc-1][tile][gi*4] =
                    make_float4(acc[gi][0], acc[gi][1], acc[gi][2], acc[gi][3]);
        }
        __syncthreads();
        if (kc == 0) {
#pragma unroll
            for (int p = 0; p < 7; p++)
#pragma unroll
                for (int gi = 0; gi < 4; gi++) {
                    float4 v = *(const float4*)&red[p][tile][gi*4];
                    acc[gi][0] += v.x; acc[gi][1] += v.y; acc[gi][2] += v.z; acc[gi][3] += v.w;
                }
#pragma unroll
            for (int gi = 0; gi < 4; gi++)
#pragma unroll
                for (int si = 0; si < 4; si++)
                    gatebuf[8*gi + gt][4*si + st] = acc[gi][si];
        }
        __syncthreads();

        if (tid < 128) {
            float gI = gatebuf[     ih_g][s_g] + xg0;
            float gF = gatebuf[8  + ih_g][s_g] + xg1;
            float gG = gatebuf[16 + ih_g][s_g] + xg2;
            float gO = gatebuf[24 + ih_g][s_g] + xg3;
            c_val = sigm(gF) * c_val + sigm(gI) * tanhf(gG);
            float hv = sigm(gO) * tanhf(c_val);
            // coalesced: lanes with consecutive ih -> 32-B segments
            __hip_atomic_store(&h_ex[(((size_t)par * 8 + dg) * 16 + s_g) * 256 + h_base + ih_g],
                               hv, __ATOMIC_RELAXED, __HIP_MEMORY_SCOPE_AGENT);
            hv_prev = hv;
            ha_prev = ((size_t)t * 64 + sbase + s_g) * 512 + dir * 256 + h_base + ih_g;
        }
        __syncthreads();   // vmcnt(0) drain -> h_ex committed at coherence point

        if (tid == 0)
            __hip_atomic_store(&flags[dg * 32 + slice], sc, __ATOMIC_RELAXED, __HIP_MEMORY_SCOPE_AGENT);

        // poll wave: nothing else outstanding -> fast first iteration
        if (tid < 64) {
            const int* fp = &flags[dg * 32 + (tid & 31)];
            int spins = 0;
            int v = __hip_atomic_load(fp, __ATOMIC_RELAXED, __HIP_MEMORY_SCOPE_AGENT);
            while (__ballot(v < sc) != 0ull) {
                if (++spins > 8) __builtin_amdgcn_s_sleep(1);
                v = __hip_atomic_load(fp, __ATOMIC_RELAXED, __HIP_MEMORY_SCOPE_AGENT);
                if (spins > (1 << 20)) break;   // safety valve; co-residency guaranteed
            }
        }
        __syncthreads();

        {   // coalesced 8-byte coherent reload -> LDS
            const float* base = &h_ex[(((size_t)par * 8 + dg) * 16) * 256];
#pragma unroll
            for (int i = 0; i < 8; i++) {
                int pos = tid + 256 * i;
                int fo  = pos << 1;
                unsigned long long u64 = __hip_atomic_load(
                    (const unsigned long long*)(base + fo), __ATOMIC_RELAXED, __HIP_MEMORY_SCOPE_AGENT);
                float2 v = __builtin_bit_cast(float2, u64);
                *(float2*)&h_lds[fo >> 8][fo & 255] = v;
            }
        }
        __syncthreads();
    }

    if (tid < 128) {
        h_all[ha_prev] = hv_prev;
        c_state[(size_t)(dir * 64 + sbase + s_g) * 256 + h_base + ih_g] = c_val;
    }
}

// ---------------------------------------------------------------------------
__global__ __launch_bounds__(256) void emis_kernel(
    const float* __restrict__ h_all, const float* __restrict__ w_out,
    const float* __restrict__ b_out, float* __restrict__ emis)
{
    const int row = blockIdx.x * 16 + (threadIdx.x >> 4);
    const int k   = threadIdx.x & 15;
    const float* hr = &h_all[(size_t)row * 512];
    const float* wr = &w_out[(size_t)(k < NTAG ? k : 0) * 512];
    float acc = 0.0f;
#pragma unroll 8
    for (int e = 0; e < 512; e += 4) {
        float4 h4 = *(const float4*)&hr[e];
        float4 w4 = *(const float4*)&wr[e];
        acc += h4.x*w4.x + h4.y*w4.y + h4.z*w4.z + h4.w*w4.w;
    }
    if (k < NTAG) emis[(size_t)row * NTAG + k] = acc + b_out[k];
}

// ---------------------------------------------------------------------------
__global__ __launch_bounds__(64) void viterbi_kernel(
    const float* __restrict__ emis, const float* __restrict__ start_trans,
    const float* __restrict__ end_trans, const float* __restrict__ trans,
    float* __restrict__ out)
{
    const int b = blockIdx.x;
    const int k = threadIdx.x;
    __shared__ float em[T_LEN * NTAG];
    __shared__ unsigned char bp[T_LEN][16];

    for (int t = k; t < T_LEN; t += 64) {
        const float* src = &emis[((size_t)t * 64 + b) * NTAG];
#pragma unroll
        for (int kk = 0; kk < NTAG; kk++)
            em[t * NTAG + kk] = src[kk];
    }
    __syncthreads();

    float tc[NTAG];
#pragma unroll
    for (int kp = 0; kp < NTAG; kp++)
        tc[kp] = (k < NTAG) ? trans[kp * NTAG + k] : 0.0f;

    float score = (k < NTAG) ? (start_trans[k] + em[k]) : -3.0e38f;

    for (int t = 1; t < T_LEN; t++) {
        float best = -3.0e38f;
        int bi = 0;
#pragma unroll
        for (int kp = 0; kp < NTAG; kp++) {
            float v = __shfl(score, kp) + tc[kp];
            if (v > best) { best = v; bi = kp; }   // strict > => first max (jnp.argmax)
        }
        if (k < NTAG) {
            score = best + em[t * NTAG + k];
            bp[t][k] = (unsigned char)bi;
        }
    }
    if (k < NTAG) score += end_trans[k];
    else score = -3.0e38f;
    __syncthreads();

    float bs = -3.0e38f;
    int tag = 0;
#pragma unroll
    for (int kk = 0; kk < NTAG; kk++) {
        float v = __shfl(score, kk);
        if (v > bs) { bs = v; tag = kk; }
    }
    if (k == 0) {
        out[32768 + b] = bs;
        int tg = tag;
        out[b * T_LEN + (T_LEN - 1)] = (float)tg;
        for (int t = T_LEN - 1; t >= 1; t--) {
            tg = bp[t][tg];
            out[b * T_LEN + t - 1] = (float)tg;
        }
    }
}

// ---------------------------------------------------------------------------
extern "C" void kernel_launch(void* const* d_in, const int* in_sizes, int n_in,
                              void* d_out, int out_size, void* d_ws, size_t ws_size,
                              hipStream_t stream)
{
    (void)in_sizes; (void)n_in; (void)out_size; (void)ws_size;
    const int*   x    = (const int*)  d_in[0];
    const float* emb  = (const float*)d_in[1];
    const float* wihf = (const float*)d_in[2];
    const float* whhf = (const float*)d_in[3];
    const float* bihf = (const float*)d_in[4];
    const float* bhhf = (const float*)d_in[5];
    const float* wihb = (const float*)d_in[6];
    const float* whhb = (const float*)d_in[7];
    const float* bihb = (const float*)d_in[8];
    const float* bhhb = (const float*)d_in[9];
    const float* wout = (const float*)d_in[10];
    const float* bout = (const float*)d_in[11];
    const float* stt  = (const float*)d_in[12];
    const float* ent  = (const float*)d_in[13];
    const float* trn  = (const float*)d_in[14];
    float* out = (float*)d_out;

    char* ws = (char*)d_ws;
    size_t off = 0;
    float* xg_ws = (float*)(ws + off); off += (size_t)2 * CT * 1024 * 64 * 4;   // 33.55 MB
    float* h_all = (float*)(ws + off); off += (size_t)T_LEN * 64 * 512 * 4;     // 67.11 MB
    float* h_ex  = (float*)(ws + off); off += (size_t)2 * 8 * 16 * 256 * 4;     // 256 KB
    float* c_st  = (float*)(ws + off); off += (size_t)2 * 64 * 256 * 4;         // 128 KB
    float* emis  = (float*)(ws + off); off += (size_t)T_LEN * 64 * NTAG * 4;    // 1.70 MB
    int*   flags = (int*)  (ws + off); off += 8 * 32 * 4;

    hipMemsetAsync(h_ex,  0, (size_t)2 * 8 * 16 * 256 * 4, stream);
    hipMemsetAsync(c_st,  0, (size_t)2 * 64 * 256 * 4, stream);
    hipMemsetAsync(flags, 0, 8 * 32 * 4, stream);

    for (int c = 0; c < NCHUNK; c++) {
        xg_gemm<<<dim3(8, 32, 2), 256, 0, stream>>>(x, emb, wihf, wihb,
                                                    bihf, bhhf, bihb, bhhb, xg_ws, c);
        lstm_chunk<<<256, 256, 0, stream>>>(xg_ws, whhf, whhb, h_ex, c_st, h_all, flags, c);
    }
    emis_kernel<<<2048, 256, 0, stream>>>(h_all, wout, bout, emis);
    viterbi_kernel<<<64, 64, 0, stream>>>(emis, stt, ent, trn, out);
}